// Round 1
// baseline (1001.056 us; speedup 1.0000x reference)
//
#include <hip/hip_runtime.h>
#include <hip/hip_bf16.h>

#define BB 256
#define LL 200
#define CC 4
#define HH 128
#define G3 384   // 3*H
#define NB 4     // batch elements per workgroup

__device__ __forceinline__ float sigmoidf_(float x) {
    return 1.0f / (1.0f + __expf(-x));
}
__device__ __forceinline__ float tanhf_(float x) {
    // tanh(x) = 2*sigmoid(2x) - 1 ; saturates correctly at +-inf
    return 2.0f / (1.0f + __expf(-2.0f * x)) - 1.0f;
}

// ---------------------------------------------------------------------------
// Pre-kernel: compute per-batch lengths from timeline_mask with bool-dtype
// detection. numpy bool => 1 byte/elem. If the harness shipped int32, the
// uint8 interpretation of rows is non-monotone (1,0,0,0 patterns) -> detect
// and re-read as int32 (in-bounds only in that case).
// ---------------------------------------------------------------------------
__global__ void compute_lens_kernel(const unsigned char* __restrict__ mask8,
                                    int* __restrict__ lens) {
    __shared__ int bad;
    int b = threadIdx.x;             // one block of 256 threads
    if (b == 0) bad = 0;
    __syncthreads();
    int cnt8 = 0, prev = 0, mono = 1;
    for (int t = 0; t < LL; ++t) {
        int v = mask8[b * LL + t] ? 1 : 0;
        cnt8 += (v == 0);
        if (v < prev) mono = 0;
        prev = v;
    }
    if (!mono) atomicAdd(&bad, 1);
    __syncthreads();
    int len;
    if (bad == 0) {
        len = cnt8;
    } else {
        const int* m32 = (const int*)mask8;
        int c = 0;
        for (int t = 0; t < LL; ++t) c += (m32[b * LL + t] == 0);
        len = c;
    }
    if (len < 1) len = 1;
    if (len > LL) len = LL;
    lens[b] = len;
}

// ---------------------------------------------------------------------------
// Fused persistent GRU. Grid (64, 4) = (b-tiles, channel). 768 threads:
//   tid 0..383  : h-threads, hold W_hh[c][g][:] in 128 VGPRs
//   tid 384..767: x-threads, hold W_ih[c][g][:] in 128 VGPRs
// ---------------------------------------------------------------------------
__global__ __launch_bounds__(768, 3) void gru_fused_kernel(
    const float* __restrict__ seqs,   // (B,L,C,H)
    const int*   __restrict__ lens,   // (B,)
    const float* __restrict__ W_ih,   // (C,384,128)
    const float* __restrict__ W_hh,   // (C,384,128)
    const float* __restrict__ b_ih,   // (C,384)
    const float* __restrict__ b_hh,   // (C,384)
    float*       __restrict__ out)    // (C,B,L,H)
{
    const int btile = blockIdx.x;          // 0..63
    const int c     = blockIdx.y;          // 0..3
    const int bbase = btile * NB;
    const int tid   = threadIdx.x;         // 0..767
    const int role  = tid / G3;            // 0 = W_hh, 1 = W_ih
    const int g     = tid % G3;

    __shared__ float hT[HH][8];            // h transposed: hT[k][b], padded row
    __shared__ float gh_lds[NB][G3];
    __shared__ float xt_lds[NB][G3];
    __shared__ float x_lds[2][NB][HH];
    __shared__ int   len_lds[NB];

    // ---- one-time setup ----
    if (tid < NB) len_lds[tid] = lens[bbase + tid];
    for (int i = tid; i < HH * 8; i += 768) ((float*)hT)[i] = 0.0f;

    // weight row -> registers (static indexing: fully unrolled)
    float w[HH];
    {
        const float* Wsrc = (role == 0 ? W_hh : W_ih) + (size_t)(c * G3 + g) * HH;
        #pragma unroll
        for (int k = 0; k < HH; k += 4) {
            float4 v = *(const float4*)(Wsrc + k);
            w[k] = v.x; w[k + 1] = v.y; w[k + 2] = v.z; w[k + 3] = v.w;
        }
    }
    const float bias = (role == 0 ? b_hh : b_ih)[c * G3 + g];

    __syncthreads();   // len_lds + hT ready

    // ---- preload x for s = 0 ----
    if (tid < 128) {
        int pb = tid >> 5, pk = (tid & 31) * 4;
        int len = len_lds[pb];
        int t0 = LL - len; if (t0 >= LL) t0 -= LL;
        float4 v = *(const float4*)&seqs[(((size_t)(bbase + pb) * LL + t0) * CC + c) * HH + pk];
        *(float4*)&x_lds[0][pb][pk] = v;
    }
    __syncthreads();

    for (int s = 0; s < LL; ++s) {
        const int cur = s & 1, nxt = cur ^ 1;

        // stage 1: issue prefetch of x for step s+1 (held in regs until after gates)
        float4 xpre;
        int pb = 0, pk = 0;
        if (tid < 128) {
            pb = tid >> 5; pk = (tid & 31) * 4;
            int len = len_lds[pb];
            int t1 = s + 1 + LL - len; if (t1 >= LL) t1 -= LL;
            xpre = *(const float4*)&seqs[(((size_t)(bbase + pb) * LL + t1) * CC + c) * HH + pk];
        }

        // stage 2: dot products (h-threads and x-threads in parallel)
        if (role == 0) {
            float a0 = 0.f, a1 = 0.f, a2 = 0.f, a3 = 0.f;
            #pragma unroll
            for (int k = 0; k < HH; ++k) {
                float4 hv = *(const float4*)&hT[k][0];   // broadcast b128
                a0 = fmaf(w[k], hv.x, a0);
                a1 = fmaf(w[k], hv.y, a1);
                a2 = fmaf(w[k], hv.z, a2);
                a3 = fmaf(w[k], hv.w, a3);
            }
            gh_lds[0][g] = a0 + bias;
            gh_lds[1][g] = a1 + bias;
            gh_lds[2][g] = a2 + bias;
            gh_lds[3][g] = a3 + bias;
        } else {
            #pragma unroll
            for (int b = 0; b < NB; ++b) {
                float a = 0.f;
                #pragma unroll
                for (int k = 0; k < HH; k += 4) {
                    float4 xv = *(const float4*)&x_lds[cur][b][k];  // broadcast b128
                    a = fmaf(w[k],     xv.x, a);
                    a = fmaf(w[k + 1], xv.y, a);
                    a = fmaf(w[k + 2], xv.z, a);
                    a = fmaf(w[k + 3], xv.w, a);
                }
                xt_lds[b][g] = a + bias;
            }
        }
        __syncthreads();   // barrier A: gh/xt visible

        // stage 3: gates + h update + output (512 threads)
        if (tid < NB * HH) {
            int b = tid >> 7, j = tid & 127;
            float xr = xt_lds[b][j],          hr = gh_lds[b][j];
            float xz = xt_lds[b][j + HH],     hz = gh_lds[b][j + HH];
            float xn = xt_lds[b][j + 2 * HH], hn = gh_lds[b][j + 2 * HH];
            float r = sigmoidf_(xr + hr);
            float z = sigmoidf_(xz + hz);
            float n = tanhf_(xn + r * hn);
            float hold = hT[j][b];
            float hnew = (1.0f - z) * n + z * hold;
            hT[j][b] = hnew;
            int len = len_lds[b];
            int t = s + LL - len; if (t >= LL) t -= LL;
            float outv = (t < len) ? hnew : 0.0f;
            out[(((size_t)c * BB + (bbase + b)) * LL + t) * HH + j] = outv;
        }
        // write the prefetched x into the next buffer (vmcnt waited here, late)
        if (tid < 128) {
            *(float4*)&x_lds[nxt][pb][pk] = xpre;
        }
        __syncthreads();   // barrier B: h + next-x visible
    }
}

extern "C" void kernel_launch(void* const* d_in, const int* in_sizes, int n_in,
                              void* d_out, int out_size, void* d_ws, size_t ws_size,
                              hipStream_t stream) {
    const float* seqs  = (const float*)d_in[0];
    const unsigned char* tmask = (const unsigned char*)d_in[1];
    // d_in[2] = attention_mask (unused, all false)
    const float* W_ih  = (const float*)d_in[3];
    const float* W_hh  = (const float*)d_in[4];
    const float* b_ih  = (const float*)d_in[5];
    const float* b_hh  = (const float*)d_in[6];
    float* out = (float*)d_out;

    int* lens = (int*)d_ws;   // 256 ints

    compute_lens_kernel<<<1, BB, 0, stream>>>(tmask, lens);

    dim3 grid(BB / NB, CC);
    gru_fused_kernel<<<grid, 768, 0, stream>>>(seqs, lens, W_ih, W_hh, b_ih, b_hh, out);
}

// Round 2
// 861.646 us; speedup vs baseline: 1.1618x; 1.1618x over previous
//
#include <hip/hip_runtime.h>
#include <hip/hip_bf16.h>

#define BB 256
#define LL 200
#define CC 4
#define HH 128
#define G3 384   // 3*H
#define NB 4     // batch elements per workgroup
#define TT 8     // steps per superstep
#define NSS (LL / TT)   // 25

__device__ __forceinline__ float sigmoidf_(float x) {
    return 1.0f / (1.0f + __expf(-x));
}
__device__ __forceinline__ float tanhf_(float x) {
    return 2.0f / (1.0f + __expf(-2.0f * x)) - 1.0f;
}

// ---------------------------------------------------------------------------
// Pre-kernel: per-batch lengths from timeline_mask with bool-dtype detection.
// ---------------------------------------------------------------------------
__global__ void compute_lens_kernel(const unsigned char* __restrict__ mask8,
                                    int* __restrict__ lens) {
    __shared__ int bad;
    int b = threadIdx.x;
    if (b == 0) bad = 0;
    __syncthreads();
    int cnt8 = 0, prev = 0, mono = 1;
    for (int t = 0; t < LL; ++t) {
        int v = mask8[b * LL + t] ? 1 : 0;
        cnt8 += (v == 0);
        if (v < prev) mono = 0;
        prev = v;
    }
    if (!mono) atomicAdd(&bad, 1);
    __syncthreads();
    int len;
    if (bad == 0) {
        len = cnt8;
    } else {
        const int* m32 = (const int*)mask8;
        int c = 0;
        for (int t = 0; t < LL; ++t) c += (m32[b * LL + t] == 0);
        len = c;
    }
    if (len < 1) len = 1;
    if (len > LL) len = LL;
    lens[b] = len;
}

// ---------------------------------------------------------------------------
// Fused persistent GRU, superstep structure.
// 768 threads = (g in 0..383) x (half in 0..1).
//   - Each thread permanently holds W_hh[c][g][half*64 .. half*64+63] in VGPRs.
//   - Phase X (once per 8 steps): thread (g, half) computes x-projections for
//     t = half*4..half*4+3, all 4 b, streaming W_ih[c][g][:] from L2 once.
//   - Phase R (per step): half-dot of W_hh row vs h (broadcast LDS reads),
//     partials combined in LDS; 512 gate-threads do the pointwise update.
// ---------------------------------------------------------------------------
__global__ __launch_bounds__(768, 3) void gru_fused_kernel(
    const float* __restrict__ seqs,   // (B,L,C,H)
    const int*   __restrict__ lens,   // (B,)
    const float* __restrict__ W_ih,   // (C,384,128)
    const float* __restrict__ W_hh,   // (C,384,128)
    const float* __restrict__ b_ih,   // (C,384)
    const float* __restrict__ b_hh,   // (C,384)
    float*       __restrict__ out)    // (C,B,L,H)
{
    const int btile = blockIdx.x;          // 0..63
    const int c     = blockIdx.y;          // 0..3
    const int bbase = btile * NB;
    const int tid   = threadIdx.x;         // 0..767
    const int g     = tid % G3;
    const int half  = tid / G3;            // 0/1

    __shared__ float x_stage[TT][NB][HH];  // 16 KB
    __shared__ float xt_buf[TT][NB][G3];   // 48 KB
    __shared__ float hT[HH][8];            // 4 KB  (hT[k][b], b<4 used)
    __shared__ float part[2][NB][G3];      // 12 KB
    __shared__ float bih_lds[G3];          // 1.5 KB
    __shared__ float bhh_lds[G3];          // 1.5 KB
    __shared__ int   len_lds[NB];

    // ---- one-time setup ----
    if (tid < NB) len_lds[tid] = lens[bbase + tid];
    for (int i = tid; i < HH * 8; i += 768) ((float*)hT)[i] = 0.0f;
    if (tid < G3) {
        bih_lds[tid] = b_ih[c * G3 + tid];
        bhh_lds[tid] = b_hh[c * G3 + tid];
    }

    // W_hh half-row -> 64 VGPRs (static indexing only)
    float wh[64];
    {
        const float* Wsrc = W_hh + ((size_t)(c * G3 + g)) * HH + half * 64;
        #pragma unroll
        for (int k = 0; k < 64; k += 4) {
            float4 v = *(const float4*)(Wsrc + k);
            wh[k] = v.x; wh[k + 1] = v.y; wh[k + 2] = v.z; wh[k + 3] = v.w;
        }
    }
    const float* wi_row = W_ih + ((size_t)(c * G3 + g)) * HH;

    __syncthreads();

    for (int ss = 0; ss < NSS; ++ss) {
        // ---- stage x for 8 steps: x_stage[dt][b][k] ----
        if (tid < 512) {
            int b  = tid >> 7;         // 0..3
            int dt = (tid >> 4) & 7;   // 0..7
            int q  = tid & 15;         // 0..15 -> k = q*8 .. q*8+7
            int len = len_lds[b];
            int t = ss * TT + dt + LL - len; if (t >= LL) t -= LL;
            const float* src = &seqs[(((size_t)(bbase + b) * LL + t) * CC + c) * HH + q * 8];
            float4 v0 = *(const float4*)(src);
            float4 v1 = *(const float4*)(src + 4);
            *(float4*)&x_stage[dt][b][q * 8]     = v0;
            *(float4*)&x_stage[dt][b][q * 8 + 4] = v1;
        }
        __syncthreads();

        // ---- phase X: xt_buf[t][b][g] for t in [half*4, half*4+4) ----
        {
            float acc[4][NB];
            #pragma unroll
            for (int i = 0; i < 4; ++i)
                #pragma unroll
                for (int j = 0; j < NB; ++j) acc[i][j] = 0.0f;

            #pragma unroll 2
            for (int k4 = 0; k4 < HH; k4 += 4) {
                float4 w4 = *(const float4*)(wi_row + k4);
                #pragma unroll
                for (int dt = 0; dt < 4; ++dt) {
                    #pragma unroll
                    for (int b = 0; b < NB; ++b) {
                        float4 xv = *(const float4*)&x_stage[half * 4 + dt][b][k4]; // broadcast
                        float a = acc[dt][b];
                        a = fmaf(w4.x, xv.x, a);
                        a = fmaf(w4.y, xv.y, a);
                        a = fmaf(w4.z, xv.z, a);
                        a = fmaf(w4.w, xv.w, a);
                        acc[dt][b] = a;
                    }
                }
            }
            #pragma unroll
            for (int dt = 0; dt < 4; ++dt)
                #pragma unroll
                for (int b = 0; b < NB; ++b)
                    xt_buf[half * 4 + dt][b][g] = acc[dt][b];
        }
        __syncthreads();

        // ---- phase R: 8 recurrent steps ----
        for (int dt = 0; dt < TT; ++dt) {
            const int s = ss * TT + dt;

            // half-dot: W_hh[g][half*64+k] * h[k]
            float a0 = 0.f, a1 = 0.f, a2 = 0.f, a3 = 0.f;
            #pragma unroll
            for (int k = 0; k < 64; ++k) {
                float4 hv = *(const float4*)&hT[half * 64 + k][0];   // broadcast
                a0 = fmaf(wh[k], hv.x, a0);
                a1 = fmaf(wh[k], hv.y, a1);
                a2 = fmaf(wh[k], hv.z, a2);
                a3 = fmaf(wh[k], hv.w, a3);
            }
            part[half][0][g] = a0;
            part[half][1][g] = a1;
            part[half][2][g] = a2;
            part[half][3][g] = a3;
            __syncthreads();   // partials + (first iter) xt_buf visible

            if (tid < NB * HH) {
                int b = tid >> 7, j = tid & 127;
                float hr = part[0][b][j]            + part[1][b][j];
                float hz = part[0][b][j + HH]       + part[1][b][j + HH];
                float hn = part[0][b][j + 2 * HH]   + part[1][b][j + 2 * HH];
                float xr = xt_buf[dt][b][j];
                float xz = xt_buf[dt][b][j + HH];
                float xn = xt_buf[dt][b][j + 2 * HH];
                float r = sigmoidf_(xr + bih_lds[j]          + hr + bhh_lds[j]);
                float z = sigmoidf_(xz + bih_lds[j + HH]     + hz + bhh_lds[j + HH]);
                float n = tanhf_(xn + bih_lds[j + 2 * HH] + r * (hn + bhh_lds[j + 2 * HH]));
                float hold = hT[j][b];
                float hnew = (1.0f - z) * n + z * hold;
                hT[j][b] = hnew;
                int len = len_lds[b];
                int t = s + LL - len; if (t >= LL) t -= LL;
                out[(((size_t)c * BB + (bbase + b)) * LL + t) * HH + j] = (t < len) ? hnew : 0.0f;
            }
            __syncthreads();   // h + xt_buf free for rewrite
        }
    }
}

extern "C" void kernel_launch(void* const* d_in, const int* in_sizes, int n_in,
                              void* d_out, int out_size, void* d_ws, size_t ws_size,
                              hipStream_t stream) {
    const float* seqs  = (const float*)d_in[0];
    const unsigned char* tmask = (const unsigned char*)d_in[1];
    // d_in[2] = attention_mask (unused, all false)
    const float* W_ih  = (const float*)d_in[3];
    const float* W_hh  = (const float*)d_in[4];
    const float* b_ih  = (const float*)d_in[5];
    const float* b_hh  = (const float*)d_in[6];
    float* out = (float*)d_out;

    int* lens = (int*)d_ws;   // 256 ints

    compute_lens_kernel<<<1, BB, 0, stream>>>(tmask, lens);

    dim3 grid(BB / NB, CC);
    gru_fused_kernel<<<grid, 768, 0, stream>>>(seqs, lens, W_ih, W_hh, b_ih, b_hh, out);
}

// Round 3
// 502.387 us; speedup vs baseline: 1.9926x; 1.7151x over previous
//
#include <hip/hip_runtime.h>
#include <hip/hip_bf16.h>

#define BB 256
#define LL 200
#define CC 4
#define HH 128
#define G3 384

typedef short bf16x8 __attribute__((ext_vector_type(8)));
typedef float f32x4 __attribute__((ext_vector_type(4)));

#define MFMA16(a, b, c) __builtin_amdgcn_mfma_f32_16x16x32_bf16((a), (b), (c), 0, 0, 0)

__device__ __forceinline__ short bf16_rne(float x) {
    union { float f; unsigned u; } v; v.f = x;
    unsigned r = v.u + 0x7FFFu + ((v.u >> 16) & 1u);
    return (short)(r >> 16);
}
__device__ __forceinline__ float bf16_tof(short b) {
    union { unsigned u; float f; } v; v.u = ((unsigned)(unsigned short)b) << 16;
    return v.f;
}
__device__ __forceinline__ float rcp_(float x) { return __builtin_amdgcn_rcpf(x); }
__device__ __forceinline__ float sigm_(float x) { return rcp_(1.0f + __expf(-x)); }
__device__ __forceinline__ float tanhf_(float x) { return 2.0f * rcp_(1.0f + __expf(-2.0f * x)) - 1.0f; }

// ---------------------------------------------------------------------------
// lengths from timeline_mask (bool-dtype detection, verified R1/R2)
// ---------------------------------------------------------------------------
__global__ void compute_lens_kernel(const unsigned char* __restrict__ mask8,
                                    int* __restrict__ lens) {
    __shared__ int bad;
    int b = threadIdx.x;
    if (b == 0) bad = 0;
    __syncthreads();
    int cnt8 = 0, prev = 0, mono = 1;
    for (int t = 0; t < LL; ++t) {
        int v = mask8[b * LL + t] ? 1 : 0;
        cnt8 += (v == 0);
        if (v < prev) mono = 0;
        prev = v;
    }
    if (!mono) atomicAdd(&bad, 1);
    __syncthreads();
    int len;
    if (bad == 0) {
        len = cnt8;
    } else {
        const int* m32 = (const int*)mask8;
        int c = 0;
        for (int t = 0; t < LL; ++t) c += (m32[b * LL + t] == 0);
        len = c;
    }
    if (len < 1) len = 1;
    if (len > LL) len = LL;
    lens[b] = len;
}

// ---------------------------------------------------------------------------
// split W -> bf16 hi + bf16 lo-residual
// ---------------------------------------------------------------------------
__global__ void wsplit_kernel(const float* __restrict__ Wih, const float* __restrict__ Whh,
                              short* __restrict__ wih_hi, short* __restrict__ wih_lo,
                              short* __restrict__ whh_hi, short* __restrict__ whh_lo) {
    int i = blockIdx.x * 256 + threadIdx.x;   // grid 768 -> 196608 = 4*384*128
    float a = Wih[i];
    short ha = bf16_rne(a);
    wih_hi[i] = ha; wih_lo[i] = bf16_rne(a - bf16_tof(ha));
    float b = Whh[i];
    short hb = bf16_rne(b);
    whh_hi[i] = hb; whh_lo[i] = bf16_rne(b - bf16_tof(hb));
}

// ---------------------------------------------------------------------------
// Kernel 1: xp[c][s][b][g] = x[b, t(b,s), c, :] . W_ih[c][g,:] + b_ih[c][g]
// split-bf16 MFMA. M-tile = 8b x 8s = 64 rows; 4 waves x 96 cols.
// ---------------------------------------------------------------------------
__global__ __launch_bounds__(256, 2) void xproj_kernel(
    const float* __restrict__ seqs, const int* __restrict__ lens,
    const short* __restrict__ wih_hi, const short* __restrict__ wih_lo,
    const float* __restrict__ b_ih, float* __restrict__ xp,
    int s_base, int CH, int nst)
{
    const int c  = blockIdx.y;
    const int bt = blockIdx.x / nst;
    const int st = blockIdx.x % nst;
    const int tid = threadIdx.x;
    const int l = tid & 63, w = tid >> 6;
    const int l15 = l & 15, l4 = l >> 4;

    __shared__ __align__(16) short Ah[64][136];   // +8 pad -> 2-way-free banks
    __shared__ __align__(16) short Al[64][136];

    // ---- stage 64 gathered rows, convert to hi/lo ----
    #pragma unroll
    for (int rd = 0; rd < 8; ++rd) {
        int row = rd * 8 + (tid >> 5);
        int b  = bt * 8 + (row >> 3);
        int sg = s_base + st * 8 + (row & 7);
        int len = lens[b];
        int t = sg + LL - len; if (t >= LL) t -= LL;
        const float* src = seqs + ((size_t)(b * LL + t) * CC + c) * HH + (tid & 31) * 4;
        float4 v = *(const float4*)src;
        short4 hv, lv;
        hv.x = bf16_rne(v.x); lv.x = bf16_rne(v.x - bf16_tof(hv.x));
        hv.y = bf16_rne(v.y); lv.y = bf16_rne(v.y - bf16_tof(hv.y));
        hv.z = bf16_rne(v.z); lv.z = bf16_rne(v.z - bf16_tof(hv.z));
        hv.w = bf16_rne(v.w); lv.w = bf16_rne(v.w - bf16_tof(hv.w));
        *(short4*)&Ah[row][(tid & 31) * 4] = hv;
        *(short4*)&Al[row][(tid & 31) * 4] = lv;
    }
    __syncthreads();

    f32x4 acc[4][6];
    #pragma unroll
    for (int m = 0; m < 4; ++m)
        #pragma unroll
        for (int nt = 0; nt < 6; ++nt) {
            acc[m][nt][0] = 0.f; acc[m][nt][1] = 0.f; acc[m][nt][2] = 0.f; acc[m][nt][3] = 0.f;
        }

    const int gbase = c * G3 + w * 96 + l15;

    #pragma unroll
    for (int ks = 0; ks < 4; ++ks) {
        bf16x8 ah[4], al[4];
        #pragma unroll
        for (int m = 0; m < 4; ++m) {
            ah[m] = *(const bf16x8*)&Ah[m * 16 + l15][ks * 32 + l4 * 8];
            al[m] = *(const bf16x8*)&Al[m * 16 + l15][ks * 32 + l4 * 8];
        }
        #pragma unroll
        for (int nt = 0; nt < 6; ++nt) {
            size_t wi = (size_t)(gbase + nt * 16) * HH + ks * 32 + l4 * 8;
            bf16x8 bh = *(const bf16x8*)(wih_hi + wi);
            bf16x8 bl = *(const bf16x8*)(wih_lo + wi);
            #pragma unroll
            for (int m = 0; m < 4; ++m) {
                acc[m][nt] = MFMA16(ah[m], bh, acc[m][nt]);
                acc[m][nt] = MFMA16(al[m], bh, acc[m][nt]);
                acc[m][nt] = MFMA16(ah[m], bl, acc[m][nt]);
            }
        }
    }

    // ---- epilogue: +bias, store to xp[c][s_loc][b][g] ----
    #pragma unroll
    for (int nt = 0; nt < 6; ++nt) {
        float bia = b_ih[gbase + nt * 16];
        #pragma unroll
        for (int m = 0; m < 4; ++m) {
            #pragma unroll
            for (int r = 0; r < 4; ++r) {
                int row = m * 16 + l4 * 4 + r;
                int b  = bt * 8 + (row >> 3);
                int sl = st * 8 + (row & 7);
                size_t o = (((size_t)c * CH + sl) * BB + b) * G3 + (w * 96 + nt * 16 + l15);
                xp[o] = acc[m][nt][r] + bia;
            }
        }
    }
}

// ---------------------------------------------------------------------------
// Kernel 2: recurrent GRU. 64 WGs (16 b-tiles x 4 c), 256 thr (4 waves).
// W_hh hi/lo fragments pinned in VGPRs; h double-buffered in LDS in MFMA
// A-fragment layout; gates fully in-lane; one raw barrier per step.
// wave w owns cols {32w..32w+31} of each gate (acc tiles 2w,2w+1,8+2w,...).
// ---------------------------------------------------------------------------
__global__ __launch_bounds__(256, 1) void gru_rec_kernel(
    const float* __restrict__ xp,
    const short* __restrict__ whh_hi, const short* __restrict__ whh_lo,
    const float* __restrict__ b_hh, const int* __restrict__ lens,
    float* __restrict__ hws, float* __restrict__ out,
    int s_base, int CH, int first)
{
    const int c = blockIdx.y, bt = blockIdx.x;
    const int tid = threadIdx.x;
    const int l = tid & 63, w = tid >> 6;
    const int l15 = l & 15, l4 = l >> 4;

    __shared__ __align__(16) short hfrag[2][2][4][512];  // [buf][hi/lo][ks][lane*8]

    // ---- persistent W_hh fragments ----
    float4 Bh4[6][4], Bl4[6][4];
    #pragma unroll
    for (int q = 0; q < 6; ++q) {
        int NT = (q < 2) ? (2 * w + q) : (q < 4) ? (8 + 2 * w + (q - 2)) : (16 + 2 * w + (q - 4));
        #pragma unroll
        for (int ks = 0; ks < 4; ++ks) {
            size_t wi = (size_t)(c * G3 + NT * 16 + l15) * HH + ks * 32 + l4 * 8;
            Bh4[q][ks] = *(const float4*)(whh_hi + wi);
            Bl4[q][ks] = *(const float4*)(whh_lo + wi);
            asm volatile("" : "+v"(Bh4[q][ks].x), "+v"(Bh4[q][ks].y), "+v"(Bh4[q][ks].z), "+v"(Bh4[q][ks].w));
            asm volatile("" : "+v"(Bl4[q][ks].x), "+v"(Bl4[q][ks].y), "+v"(Bl4[q][ks].z), "+v"(Bl4[q][ks].w));
        }
    }

    // ---- biases, lengths, t-counters, h ----
    float bR[2], bZ[2], bN[2];
    #pragma unroll
    for (int cp = 0; cp < 2; ++cp) {
        int col = 32 * w + cp * 16 + l15;
        bR[cp] = b_hh[c * G3 + col];
        bZ[cp] = b_hh[c * G3 + 128 + col];
        bN[cp] = b_hh[c * G3 + 256 + col];
    }
    int lenr[4], tcur[4];
    #pragma unroll
    for (int r = 0; r < 4; ++r) {
        int b = bt * 16 + l4 * 4 + r;
        lenr[r] = lens[b];
        int t0 = s_base + LL - lenr[r]; if (t0 >= LL) t0 -= LL;
        tcur[r] = t0;
    }
    float hold[2][4];
    if (first) {
        #pragma unroll
        for (int cp = 0; cp < 2; ++cp)
            #pragma unroll
            for (int r = 0; r < 4; ++r) hold[cp][r] = 0.f;
    } else {
        #pragma unroll
        for (int cp = 0; cp < 2; ++cp)
            #pragma unroll
            for (int r = 0; r < 4; ++r)
                hold[cp][r] = hws[(size_t)(c * BB + bt * 16 + l4 * 4 + r) * HH + 32 * w + cp * 16 + l15];
    }
    #pragma unroll
    for (int cp = 0; cp < 2; ++cp)
        #pragma unroll
        for (int r = 0; r < 4; ++r) {
            short hi = bf16_rne(hold[cp][r]);
            short lo = bf16_rne(hold[cp][r] - bf16_tof(hi));
            int slot = (l4 * 4 + r + 16 * (2 * cp + (l15 >> 3))) * 8 + (l & 7);
            hfrag[0][0][w][slot] = hi;
            hfrag[0][1][w][slot] = lo;
        }
    __syncthreads();

    // ---- prologue xp load (s_loc = 0) ----
    float xpv[3][2][4];
    {
        const float* xb = xp + (size_t)c * CH * (BB * G3) + (size_t)(bt * 16 + l4 * 4) * G3 + 32 * w + l15;
        #pragma unroll
        for (int G = 0; G < 3; ++G)
            #pragma unroll
            for (int cp = 0; cp < 2; ++cp)
                #pragma unroll
                for (int r = 0; r < 4; ++r)
                    xpv[G][cp][r] = xb[(size_t)r * G3 + G * 128 + cp * 16];
    }

    for (int si = 0; si < CH; ++si) {
        const int cur = si & 1;

        // A-fragments (h hi/lo, fragment-linear layout: conflict-free b128)
        bf16x8 ah[4], al[4];
        #pragma unroll
        for (int ks = 0; ks < 4; ++ks) {
            ah[ks] = *(const bf16x8*)&hfrag[cur][0][ks][l * 8];
            al[ks] = *(const bf16x8*)&hfrag[cur][1][ks][l * 8];
        }

        f32x4 acc[6];
        #pragma unroll
        for (int q = 0; q < 6; ++q) { acc[q][0] = 0.f; acc[q][1] = 0.f; acc[q][2] = 0.f; acc[q][3] = 0.f; }

        #pragma unroll
        for (int ks = 0; ks < 4; ++ks) {
            #pragma unroll
            for (int q = 0; q < 6; ++q) {
                bf16x8 bh, bl;
                __builtin_memcpy(&bh, &Bh4[q][ks], 16);
                __builtin_memcpy(&bl, &Bl4[q][ks], 16);
                acc[q] = MFMA16(ah[ks], bh, acc[q]);
                acc[q] = MFMA16(al[ks], bh, acc[q]);
                acc[q] = MFMA16(ah[ks], bl, acc[q]);
            }
        }

        // gates: everything in-lane
        float hnew[2][4];
        #pragma unroll
        for (int cp = 0; cp < 2; ++cp)
            #pragma unroll
            for (int r = 0; r < 4; ++r) {
                float gr = sigm_(acc[cp][r] + bR[cp] + xpv[0][cp][r]);
                float gz = sigm_(acc[2 + cp][r] + bZ[cp] + xpv[1][cp][r]);
                float gn = tanhf_(xpv[2][cp][r] + gr * (acc[4 + cp][r] + bN[cp]));
                float hv = gn + gz * (hold[cp][r] - gn);
                hnew[cp][r] = hv;
                hold[cp][r] = hv;
            }

        // prefetch xp for next step (hidden under next iter's MFMA)
        if (si + 1 < CH) {
            const float* xb = xp + ((size_t)c * CH + (si + 1)) * (BB * G3) + (size_t)(bt * 16 + l4 * 4) * G3 + 32 * w + l15;
            #pragma unroll
            for (int G = 0; G < 3; ++G)
                #pragma unroll
                for (int cp = 0; cp < 2; ++cp)
                    #pragma unroll
                    for (int r = 0; r < 4; ++r)
                        xpv[G][cp][r] = xb[(size_t)r * G3 + G * 128 + cp * 16];
        }

        // write h (hi/lo) into next buffer in A-fragment layout
        #pragma unroll
        for (int cp = 0; cp < 2; ++cp)
            #pragma unroll
            for (int r = 0; r < 4; ++r) {
                short hi = bf16_rne(hold[cp][r]);
                short lo = bf16_rne(hold[cp][r] - bf16_tof(hi));
                int slot = (l4 * 4 + r + 16 * (2 * cp + (l15 >> 3))) * 8 + (l & 7);
                hfrag[cur ^ 1][0][w][slot] = hi;
                hfrag[cur ^ 1][1][w][slot] = lo;
            }

        // output store (scatter to t, zero-masked)
        #pragma unroll
        for (int r = 0; r < 4; ++r) {
            int t = tcur[r];
            int valid = t < lenr[r];
            size_t obase = ((size_t)(c * BB + bt * 16 + l4 * 4 + r) * LL + t) * HH + 32 * w + l15;
            out[obase]      = valid ? hnew[0][r] : 0.0f;
            out[obase + 16] = valid ? hnew[1][r] : 0.0f;
            tcur[r] = (t + 1 == LL) ? 0 : t + 1;
        }

        // lgkm-only drain + raw barrier: keeps xp loads / out stores in flight
        asm volatile("s_waitcnt lgkmcnt(0)" ::: "memory");
        __builtin_amdgcn_s_barrier();
        __builtin_amdgcn_sched_barrier(0);
        asm volatile("" ::: "memory");
    }

    // save h for next chunk
    #pragma unroll
    for (int cp = 0; cp < 2; ++cp)
        #pragma unroll
        for (int r = 0; r < 4; ++r)
            hws[(size_t)(c * BB + bt * 16 + l4 * 4 + r) * HH + 32 * w + cp * 16 + l15] = hold[cp][r];
}

extern "C" void kernel_launch(void* const* d_in, const int* in_sizes, int n_in,
                              void* d_out, int out_size, void* d_ws, size_t ws_size,
                              hipStream_t stream) {
    const float* seqs  = (const float*)d_in[0];
    const unsigned char* tmask = (const unsigned char*)d_in[1];
    // d_in[2] = attention_mask (all false, unused)
    const float* W_ih  = (const float*)d_in[3];
    const float* W_hh  = (const float*)d_in[4];
    const float* b_ih  = (const float*)d_in[5];
    const float* b_hh  = (const float*)d_in[6];
    float* out = (float*)d_out;

    char* ws = (char*)d_ws;
    int*   lens   = (int*)(ws);                     // 1 KB
    float* hws    = (float*)(ws + 1024);            // 512 KB
    short* wih_hi = (short*)(ws + 525312);          // 384 KB each
    short* wih_lo = (short*)(ws + 918528);
    short* whh_hi = (short*)(ws + 1311744);
    short* whh_lo = (short*)(ws + 1704960);
    float* xp     = (float*)(ws + 2098176);

    const size_t per_s = (size_t)CC * BB * G3 * 4;  // 1,572,864 B per step
    int CH;
    if (ws_size >= 2098176 + 200 * per_s)      CH = 200;
    else if (ws_size >= 2098176 + 40 * per_s)  CH = 40;
    else                                        CH = 8;
    const int nchunk = LL / CH;
    const int nst = CH / 8;

    compute_lens_kernel<<<1, BB, 0, stream>>>(tmask, lens);
    wsplit_kernel<<<768, 256, 0, stream>>>(W_ih, W_hh, wih_hi, wih_lo, whh_hi, whh_lo);

    for (int q = 0; q < nchunk; ++q) {
        xproj_kernel<<<dim3(32 * nst, CC), 256, 0, stream>>>(
            seqs, lens, wih_hi, wih_lo, b_ih, xp, q * CH, CH, nst);
        gru_rec_kernel<<<dim3(16, CC), 256, 0, stream>>>(
            xp, whh_hi, whh_lo, b_hh, lens, hws, out, q * CH, CH, q == 0);
    }
}